// Round 3
// baseline (443.557 us; speedup 1.0000x reference)
//
#include <hip/hip_runtime.h>
#include <hip/hip_bf16.h>

// Problem constants
#define NB    8
#define SQN   2048
#define SKN   4096
#define DDIM  512
#define DVDIM 256
#define NROWS (NB*SQN)      // 16384
#define SPLIT 2
#define SKH   (SKN/SPLIT)   // 2048 keys per split
#define NJ    (SKH/64)      // 32 j-iterations

typedef __attribute__((ext_vector_type(8))) short bf16x8;   // 8 bf16 = 4 VGPRs (MFMA A/B frag)
typedef __attribute__((ext_vector_type(4))) short bf16x4;
typedef __attribute__((ext_vector_type(4))) float f32x4;    // MFMA C/D frag

// fp32 -> bf16 round-to-nearest-even, bit pattern as short
__device__ __forceinline__ short f2bf(float f) {
    unsigned u = __float_as_uint(f);
    return (short)((u + 0x7FFFu + ((u >> 16) & 1u)) >> 16);
}

// async global->LDS, 16B per lane; LDS dst = wave-uniform base + lane*16
__device__ __forceinline__ void gload_lds16(const void* g, void* l) {
    __builtin_amdgcn_global_load_lds(
        (const __attribute__((address_space(1))) unsigned int*)g,
        (__attribute__((address_space(3))) unsigned int*)l, 16, 0, 0);
}

// ---------------------------------------------------------------------------
// Swizzled workspace layouts (16B chunk = 8 bf16), so linear global_load_lds
// staging lands pre-swizzled data in LDS:
//  Ks: per (sk_blk = sk/64, c = d/128) region of 1024 chunks:
//     chunk L holds key[sk_blk*64 + L/16][c*128 + ((L&15)^((L/16)&15))*8 ..+8]
//     (the 4 c-regions of one sk_blk are contiguous: 32768 shorts = 64 KB)
//  Vs: per sk_blk region of 2048 chunks:
//     chunk L holds vt[L/8][sk_blk*64 + ((L&7)^((L/8)&7))*8 ..+8]
// ---------------------------------------------------------------------------

// Generic NT GEMM: C[m][n] = sum_k A[m][k]*B[n][k], A:MxK f32, B:NxK f32.
// Epilogue writes bf16 into swizzled layout per `mode` (0 = Ks, 1 = Vs).
// Tiles 64x64, block=256 (4 waves x 16 rows), Kc=128. grid = (M/64, N/64)
__global__ __launch_bounds__(256, 2) void gemm_nt_f32_bf16_swz(
    const float* __restrict__ A, const float* __restrict__ Bm,
    unsigned short* __restrict__ C, int M, int N, int K, int mode)
{
    __shared__ short sA[64*128];   // 16 KB
    __shared__ short sB[64*128];   // 16 KB
    const int tid  = threadIdx.x;
    const int wave = tid >> 6;
    const int lane = tid & 63;
    const int quad = lane >> 4;
    const int l15  = lane & 15;
    const int m0 = blockIdx.x * 64;
    const int n0 = blockIdx.y * 64;

    f32x4 acc[4];
    #pragma unroll
    for (int n = 0; n < 4; ++n) { acc[n][0]=0.f; acc[n][1]=0.f; acc[n][2]=0.f; acc[n][3]=0.f; }

    for (int kc = 0; kc < K; kc += 128) {
        __syncthreads();
        #pragma unroll
        for (int it = 0; it < 8; ++it) {
            int f = it*1024 + tid*4;          // element index in 64x128 tile
            int row = f >> 7, col = f & 127;
            float4 av = *(const float4*)(A + (size_t)(m0+row)*K + kc + col);
            bf16x4 a4; a4[0]=f2bf(av.x); a4[1]=f2bf(av.y); a4[2]=f2bf(av.z); a4[3]=f2bf(av.w);
            *(bf16x4*)(sA + f) = a4;
            float4 bv = *(const float4*)(Bm + (size_t)(n0+row)*K + kc + col);
            bf16x4 b4; b4[0]=f2bf(bv.x); b4[1]=f2bf(bv.y); b4[2]=f2bf(bv.z); b4[3]=f2bf(bv.w);
            *(bf16x4*)(sB + f) = b4;
        }
        __syncthreads();
        #pragma unroll
        for (int t = 0; t < 4; ++t) {
            bf16x8 af = *(const bf16x8*)(sA + (wave*16 + l15)*128 + t*32 + quad*8);
            #pragma unroll
            for (int n = 0; n < 4; ++n) {
                bf16x8 bfr = *(const bf16x8*)(sB + (n*16 + l15)*128 + t*32 + quad*8);
                acc[n] = __builtin_amdgcn_mfma_f32_16x16x32_bf16(af, bfr, acc[n], 0, 0, 0);
            }
        }
    }
    // epilogue: D row=quad*4+r, col=l15; scatter 2B stores into swizzled layout
    #pragma unroll
    for (int n = 0; n < 4; ++n)
        #pragma unroll
        for (int r = 0; r < 4; ++r) {
            int m  = m0 + wave*16 + quad*4 + r;
            int nn = n0 + n*16 + l15;
            size_t idx;
            if (mode == 0) {  // Ks: key[m=sk][nn=d]
                idx = ((size_t)(m>>6)*4 + (nn>>7))*8192
                    + (size_t)((m&63)*16 + (((nn>>3)&15) ^ (m&15)))*8 + (nn&7);
            } else {          // Vs: vt[m=dv][nn=sk]
                idx = (size_t)(nn>>6)*16384
                    + (size_t)(m*8 + (((nn>>3)&7) ^ (m&7)))*8 + (nn&7);
            }
            C[idx] = (unsigned short)f2bf(acc[n][r]);
        }
}

// ---------------------------------------------------------------------------
// Fused attention: grid = (NROWS/128, SPLIT), block = 256 (4 waves x 32 rows).
//  Per wave: 32 Q rows as 2x16 (two A-frag sets share each B-frag read -> 2x
//  LDS-traffic reduction). Full K tile (64 keys x 512 d, 64 KB) staged once
//  per j-iter; V double-buffered (2x32 KB); K(j+1)/V(j+1) prefetched after
//  the QK phase so the drain overlaps PV. 144 KB LDS, 1 block/CU.
// ---------------------------------------------------------------------------
__global__ __launch_bounds__(256, 1) void attn_fused(
    const float* __restrict__ X,            // [16384][512] fp32
    const unsigned short* __restrict__ Kb,  // key bf16, Ks swizzled layout
    const unsigned short* __restrict__ Vt,  // V^T bf16, Vs swizzled layout
    float* __restrict__ Opart,              // [SPLIT][16384][256]
    float* __restrict__ Mpart,              // [SPLIT][16384]
    float* __restrict__ Lpart)              // [SPLIT][16384]
{
    __shared__ short sK[32768];     // 64 KB: K(j), 64 keys x 512 d, Ks-swizzled
    __shared__ short sV[2][16384];  // 2x32 KB: V^T 256 x 64, Vs-swizzled, dbuf
    __shared__ short sP[8192];      // 16 KB: P, 4 waves x 32 rows x 64 keys
    const int tid  = threadIdx.x;
    const int wave = tid >> 6;
    const int lane = tid & 63;
    const int quad = lane >> 4;
    const int l15  = lane & 15;
    const int l7   = lane & 7;
    const int split = blockIdx.y;
    const int q0   = blockIdx.x * 128 + wave * 32;   // wave's first Q row
    const int sb0  = split * NJ;                     // first sk_blk
    const float scale = 0.04419417382415922f;        // 1/sqrt(512)

    // Q fragments (scale folded): qf[rh][t] covers rows q0+rh*16+l15, k=t*32+quad*8..+8
    bf16x8 qf[2][16];
    #pragma unroll
    for (int rh = 0; rh < 2; ++rh) {
        const float* xrow = X + (size_t)(q0 + rh*16 + l15) * DDIM;
        #pragma unroll
        for (int t = 0; t < 16; ++t) {
            float4 a = *(const float4*)(xrow + t*32 + quad*8);
            float4 b = *(const float4*)(xrow + t*32 + quad*8 + 4);
            bf16x8 q;
            q[0]=f2bf(a.x*scale); q[1]=f2bf(a.y*scale); q[2]=f2bf(a.z*scale); q[3]=f2bf(a.w*scale);
            q[4]=f2bf(b.x*scale); q[5]=f2bf(b.y*scale); q[6]=f2bf(b.z*scale); q[7]=f2bf(b.w*scale);
            qf[rh][t] = q;
        }
    }

    f32x4 o[2][16];
    #pragma unroll
    for (int rh = 0; rh < 2; ++rh)
        #pragma unroll
        for (int i = 0; i < 16; ++i) { o[rh][i][0]=0.f; o[rh][i][1]=0.f; o[rh][i][2]=0.f; o[rh][i][3]=0.f; }
    float m_r[2][4] = {{-1e30f,-1e30f,-1e30f,-1e30f},{-1e30f,-1e30f,-1e30f,-1e30f}};
    float l_r[2][4] = {{0.f,0.f,0.f,0.f},{0.f,0.f,0.f,0.f}};
    short* sPw = sP + wave*2048;

    // prologue: stage K(0) and V(0)
    {
        const unsigned short* kb = Kb + (size_t)sb0 * 32768;
        #pragma unroll
        for (int it = 0; it < 16; ++it)
            gload_lds16(kb + it*2048 + tid*8, (char*)sK + it*4096 + wave*1024);
        const unsigned short* vb = Vt + (size_t)sb0 * 16384;
        #pragma unroll
        for (int it = 0; it < 8; ++it)
            gload_lds16(vb + it*2048 + tid*8, (char*)sV[0] + it*4096 + wave*1024);
    }
    __syncthreads();   // drain prologue stages

    for (int j = 0; j < NJ; ++j) {
        // ---- QK: S[2][64] += Q * K^T over full d=512 ----
        f32x4 s[2][4];
        #pragma unroll
        for (int rh = 0; rh < 2; ++rh)
            #pragma unroll
            for (int n = 0; n < 4; ++n) { s[rh][n][0]=0.f; s[rh][n][1]=0.f; s[rh][n][2]=0.f; s[rh][n][3]=0.f; }
        #pragma unroll
        for (int t = 0; t < 16; ++t) {
            const int cx = ((((t&3)*4 + quad) ^ l15) << 3);
            const int cbase = (t>>2)*8192 + cx;
            #pragma unroll
            for (int n = 0; n < 4; ++n) {
                bf16x8 bfr = *(const bf16x8*)(sK + cbase + (n*16 + l15)*128);
                s[0][n] = __builtin_amdgcn_mfma_f32_16x16x32_bf16(qf[0][t], bfr, s[0][n], 0, 0, 0);
                s[1][n] = __builtin_amdgcn_mfma_f32_16x16x32_bf16(qf[1][t], bfr, s[1][n], 0, 0, 0);
            }
        }

        // ---- online softmax (rows = rh*16 + quad*4 + r) ----
        float alpha[2][4];
        float p[2][4][4];
        int need_rescale = 0;
        #pragma unroll
        for (int rh = 0; rh < 2; ++rh)
            #pragma unroll
            for (int r = 0; r < 4; ++r) {
                float v = fmaxf(fmaxf(s[rh][0][r], s[rh][1][r]), fmaxf(s[rh][2][r], s[rh][3][r]));
                v = fmaxf(v, __shfl_xor(v, 1));
                v = fmaxf(v, __shfl_xor(v, 2));
                v = fmaxf(v, __shfl_xor(v, 4));
                v = fmaxf(v, __shfl_xor(v, 8));
                float mn = fmaxf(m_r[rh][r], v);
                float a  = __expf(m_r[rh][r] - mn);
                alpha[rh][r] = a;
                need_rescale |= (a < 1.0f);
                m_r[rh][r] = mn;
                float sum = 0.f;
                #pragma unroll
                for (int n = 0; n < 4; ++n) {
                    float pv = __expf(s[rh][n][r] - mn);
                    p[rh][n][r] = pv;
                    sum += pv;
                }
                sum += __shfl_xor(sum, 1);
                sum += __shfl_xor(sum, 2);
                sum += __shfl_xor(sum, 4);
                sum += __shfl_xor(sum, 8);
                l_r[rh][r] = l_r[rh][r]*a + sum;
            }
        if (__any(need_rescale)) {
            #pragma unroll
            for (int rh = 0; rh < 2; ++rh)
                #pragma unroll
                for (int n2 = 0; n2 < 16; ++n2)
                    #pragma unroll
                    for (int r = 0; r < 4; ++r) o[rh][n2][r] *= alpha[rh][r];
        }
        // P -> wave-private LDS (swizzled); same-wave read below, no barrier
        #pragma unroll
        for (int rh = 0; rh < 2; ++rh)
            #pragma unroll
            for (int n = 0; n < 4; ++n)
                #pragma unroll
                for (int r = 0; r < 4; ++r) {
                    int row = rh*16 + quad*4 + r;
                    int cch = n*2 + (l15 >> 3);
                    sPw[row*64 + ((cch ^ (row & 7)) << 3) + l7] = f2bf(p[rh][n][r]);
                }

        __syncthreads();   // all waves done reading sK -> safe to overwrite
        // prefetch K(j+1), V(j+1); drains during PV below
        if (j + 1 < NJ) {
            const unsigned short* kb = Kb + (size_t)(sb0 + j + 1) * 32768;
            #pragma unroll
            for (int it = 0; it < 16; ++it)
                gload_lds16(kb + it*2048 + tid*8, (char*)sK + it*4096 + wave*1024);
            const unsigned short* vb = Vt + (size_t)(sb0 + j + 1) * 16384;
            char* vdst = (char*)sV[(j + 1) & 1];
            #pragma unroll
            for (int it = 0; it < 8; ++it)
                gload_lds16(vb + it*2048 + tid*8, vdst + it*4096 + wave*1024);
        }

        // ---- PV: O += P * V^T from sV[j&1] ----
        const short* sVp = sV[j & 1];
        #pragma unroll
        for (int t2 = 0; t2 < 2; ++t2) {
            const int cx = (((t2*4 + quad) ^ l7) << 3);
            bf16x8 a0 = *(const bf16x8*)(sPw + l15*64 + cx);
            bf16x8 a1 = *(const bf16x8*)(sPw + (16 + l15)*64 + cx);
            #pragma unroll
            for (int n2 = 0; n2 < 16; ++n2) {
                bf16x8 bfr = *(const bf16x8*)(sVp + (n2*16 + l15)*64 + cx);
                o[0][n2] = __builtin_amdgcn_mfma_f32_16x16x32_bf16(a0, bfr, o[0][n2], 0, 0, 0);
                o[1][n2] = __builtin_amdgcn_mfma_f32_16x16x32_bf16(a1, bfr, o[1][n2], 0, 0, 0);
            }
        }
        if (j + 1 < NJ) __syncthreads();   // drain prefetch + protect sV[(j+1)&1]
    }

    // epilogue: unnormalized O + (m,l) per row
    const size_t base = (size_t)split * NROWS;
    #pragma unroll
    for (int rh = 0; rh < 2; ++rh)
        #pragma unroll
        for (int r = 0; r < 4; ++r) {
            int row = q0 + rh*16 + quad*4 + r;
            if (l15 == 0) { Mpart[base + row] = m_r[rh][r]; Lpart[base + row] = l_r[rh][r]; }
            float* orow = Opart + (base + row) * (size_t)DVDIM;
            #pragma unroll
            for (int n2 = 0; n2 < 16; ++n2)
                orow[n2*16 + l15] = o[rh][n2][r];
        }
}

// ---------------------------------------------------------------------------
// Combine the two SK-split partials: out = (O0*w0 + O1*w1)/(l0*w0 + l1*w1)
// grid = NROWS, block = 256 (= DV)
// ---------------------------------------------------------------------------
__global__ void combine_splits(
    const float* __restrict__ Opart, const float* __restrict__ Mpart,
    const float* __restrict__ Lpart, float* __restrict__ out)
{
    const int row = blockIdx.x;
    const int dv  = threadIdx.x;
    const size_t idx = (size_t)row * DVDIM + dv;
    float m0 = Mpart[row],         m1 = Mpart[NROWS + row];
    float l0 = Lpart[row],         l1 = Lpart[NROWS + row];
    float M  = fmaxf(m0, m1);
    float w0 = __expf(m0 - M), w1 = __expf(m1 - M);
    float denom = l0*w0 + l1*w1;
    float o0 = Opart[idx];
    float o1 = Opart[(size_t)NROWS*DVDIM + idx];
    out[idx] = (o0*w0 + o1*w1) / denom;
}

extern "C" void kernel_launch(void* const* d_in, const int* in_sizes, int n_in,
                              void* d_out, int out_size, void* d_ws, size_t ws_size,
                              hipStream_t stream) {
    const float* X  = (const float*)d_in[0];   // [8,2048,512]
    const float* Y  = (const float*)d_in[1];   // [4096,512]
    const float* Z  = (const float*)d_in[2];   // [4096,512]
    const float* Wk = (const float*)d_in[3];   // [512,512]
    const float* Wv = (const float*)d_in[4];   // [256,512]
    float* out = (float*)d_out;

    // workspace layout (~40.3 MB total)
    char* ws = (char*)d_ws;
    unsigned short* keyb = (unsigned short*)(ws);                  // 4 MB: Ks swizzled
    unsigned short* vtb  = (unsigned short*)(ws + (4u<<20));       // 2 MB: Vs swizzled
    float* Opart = (float*)(ws + (8u<<20));                        // 32 MB
    float* Mpart = (float*)(ws + (8u<<20) + 33554432u);            // 128 KB
    float* Lpart = (float*)(ws + (8u<<20) + 33554432u + 131072u);  // 128 KB

    // key[s][d] = sum_c Y[s][c] * Wk[d][c]  -> Ks swizzled
    gemm_nt_f32_bf16_swz<<<dim3(SKN/64, DDIM/64), dim3(256), 0, stream>>>(
        Y, Wk, keyb, SKN, DDIM, DDIM, 0);
    // vt[d][s] = sum_c Wv[d][c] * Z[s][c]   -> Vs swizzled
    gemm_nt_f32_bf16_swz<<<dim3(DVDIM/64, SKN/64), dim3(256), 0, stream>>>(
        Wv, Z, vtb, DVDIM, SKN, DDIM, 1);
    // fused attention over SK split halves
    attn_fused<<<dim3(NROWS/128, SPLIT), dim3(256), 0, stream>>>(
        X, keyb, vtb, Opart, Mpart, Lpart);
    // merge splits
    combine_splits<<<dim3(NROWS), dim3(256), 0, stream>>>(Opart, Mpart, Lpart, out);
}